// Round 1
// baseline (304.334 us; speedup 1.0000x reference)
//
#include <hip/hip_runtime.h>
#include <hip/hip_bf16.h>
#include <stdint.h>

// Problem constants (from reference setup_inputs)
#define BATCH 256
#define PSEL  128
#define IN_DIM 3200
#define O1_DIM 8192
#define O3_DIM 4096

// ---------------------------------------------------------------------------
// init: out = -8.0 (final bias folded in, atomics accumulate on top),
//       stats accumulators (4 x 256 floats) = 0
// ---------------------------------------------------------------------------
__global__ __launch_bounds__(256) void init_kernel(float* __restrict__ out,
                                                   float* __restrict__ stats) {
    int i = blockIdx.x * 256 + threadIdx.x;   // grid = 256 blocks -> 65536 == out_size
    out[i] = -8.0f;
    if (i < 1024) stats[i] = 0.0f;
}

// ---------------------------------------------------------------------------
// transpose x [256, 3200] -> xT [3200, 256]  (tiled, conflict-free)
// ---------------------------------------------------------------------------
__global__ __launch_bounds__(256) void transpose_kernel(const float* __restrict__ x,
                                                        float* __restrict__ xT) {
    __shared__ float tile[32][33];
    int i0 = blockIdx.x * 32;   // input-dim tile (3200/32 = 100)
    int b0 = blockIdx.y * 32;   // batch tile    (256/32 = 8)
    int tx = threadIdx.x;       // 32
    int ty = threadIdx.y;       // 8
#pragma unroll
    for (int k = 0; k < 4; ++k)
        tile[ty + k * 8][tx] = x[(size_t)(b0 + ty + k * 8) * IN_DIM + i0 + tx];
    __syncthreads();
#pragma unroll
    for (int k = 0; k < 4; ++k)
        xT[(size_t)(i0 + ty + k * 8) * BATCH + b0 + tx] = tile[tx][ty + k * 8];
}

// ---------------------------------------------------------------------------
// stats: per-batch-column sum and sum-of-squares of hT [N, 256]
// grid = 256 blocks, each handles N/256 contiguous rows; coalesced reads.
// ---------------------------------------------------------------------------
__global__ __launch_bounds__(256) void stats_kernel(const float* __restrict__ hT,
                                                    float* __restrict__ gsum,
                                                    float* __restrict__ gsq,
                                                    int rows_per_block) {
    int t = threadIdx.x;
    const float* p = hT + (size_t)blockIdx.x * rows_per_block * BATCH + t;
    float s = 0.0f, q = 0.0f;
    for (int r = 0; r < rows_per_block; ++r) {
        float v = p[(size_t)r * BATCH];
        s += v;
        q = fmaf(v, v, q);
    }
    atomicAdd(&gsum[t], s);
    atomicAdd(&gsq[t], q);
}

// ---------------------------------------------------------------------------
// popcnt layer: one block per output o, thread t = batch element.
//   acc_t = sum_p A_p * actT[sel[o,p]*256 + t]
// With NORM, layernorm of the INPUT is folded algebraically:
//   sum_p w_p*((v-mu)*rs*g_p + be_p) = rs*acc + sumC - rs*mu*sumA
// where A_p = sigmoid(w_p)*g_p, C_p = sigmoid(w_p)*be_p.
// FINAL: atomicAdd sigmoid into out[b*256 + o/16] (pre-init'd to -8).
// ---------------------------------------------------------------------------
template <bool NORM, bool FINAL>
__global__ __launch_bounds__(256) void popcnt_kernel(
    const float* __restrict__ actT,   // [Nin, 256]
    const int* __restrict__ sel,      // [Nout, 128]
    const float* __restrict__ w,      // [Nout, 128]
    const float* __restrict__ bias,   // [Nout]
    const float* __restrict__ g,      // [Nin]  (NORM only)
    const float* __restrict__ be,     // [Nin]  (NORM only)
    const float* __restrict__ gsum,   // [256]  (NORM only)
    const float* __restrict__ gsq,    // [256]  (NORM only)
    float inv_n,                      // 1/Nin  (NORM only)
    float* __restrict__ outp)         // [Nout,256] or final [256,256]
{
    const int o = blockIdx.x;
    const int t = threadIdx.x;

    __shared__ alignas(16) uint32_t s_pair[2 * PSEL];  // {byte_offset, A_p} interleaved
    __shared__ float s_rA[PSEL], s_rC[PSEL];
    __shared__ float s_sums[2];

    if (t < PSEL) {
        int idx = sel[o * PSEL + t];
        float ww = w[o * PSEL + t];
        float sw = 1.0f / (1.0f + __expf(-ww));   // resilu(w) == sigmoid(w)
        float a, c;
        if (NORM) {
            a = sw * g[idx];
            c = sw * be[idx];
        } else {
            a = sw;
            c = 0.0f;
        }
        s_pair[2 * t]     = (uint32_t)idx << 10;  // idx * 256 floats * 4 B
        s_pair[2 * t + 1] = __float_as_uint(a);
        if (NORM) { s_rA[t] = a; s_rC[t] = c; }
    }
    __syncthreads();

    if (NORM) {
        if (t < 64) {                 // wave 0 reduces sumA, sumC
            float va = s_rA[t] + s_rA[t + 64];
            float vc = s_rC[t] + s_rC[t + 64];
#pragma unroll
            for (int off = 32; off > 0; off >>= 1) {
                va += __shfl_down(va, off);
                vc += __shfl_down(vc, off);
            }
            if (t == 0) { s_sums[0] = va; s_sums[1] = vc; }
        }
    }

    // Main gather loop: 128 coalesced 1KB-row loads, LDS broadcast of pairs.
    const char* base = (const char*)actT + (uint32_t)(t * 4);
    const uint4* pairs = (const uint4*)s_pair;
    float acc = 0.0f;
#pragma unroll 8
    for (int p2 = 0; p2 < PSEL / 2; ++p2) {
        uint4 pr = pairs[p2];
        float v0 = *(const float*)(base + pr.x);
        float v1 = *(const float*)(base + pr.z);
        acc = fmaf(__uint_as_float(pr.y), v0, acc);
        acc = fmaf(__uint_as_float(pr.w), v1, acc);
    }
    __syncthreads();   // s_sums visible to all before epilogue

    float z;
    if (NORM) {
        float m  = gsum[t] * inv_n;
        float q  = gsq[t] * inv_n;
        float rs = rsqrtf(q - m * m + 1e-12f);
        z = rs * acc + s_sums[1] - rs * m * s_sums[0] - bias[o];
    } else {
        z = acc - bias[o];
    }
    float h = 1.0f / (1.0f + __expf(-z));

    if (FINAL) {
        atomicAdd(&outp[t * 256 + (o >> 4)], h);   // out[b, o/16], init'd to -8
    } else {
        outp[(size_t)o * BATCH + t] = h;
    }
}

// ---------------------------------------------------------------------------
extern "C" void kernel_launch(void* const* d_in, const int* in_sizes, int n_in,
                              void* d_out, int out_size, void* d_ws, size_t ws_size,
                              hipStream_t stream) {
    const float* x    = (const float*)d_in[0];
    const int*   sel1 = (const int*)d_in[1];
    const float* w1   = (const float*)d_in[2];
    const float* b1   = (const float*)d_in[3];
    const float* g1   = (const float*)d_in[4];
    const float* be1  = (const float*)d_in[5];
    const int*   sel2 = (const int*)d_in[6];
    const float* w2   = (const float*)d_in[7];
    const float* b2   = (const float*)d_in[8];
    const float* g2   = (const float*)d_in[9];
    const float* be2  = (const float*)d_in[10];
    const int*   sel3 = (const int*)d_in[11];
    const float* w3   = (const float*)d_in[12];
    const float* b3   = (const float*)d_in[13];
    float* out = (float*)d_out;

    // workspace layout
    char* ws = (char*)d_ws;
    float* xT    = (float*)(ws);                                     // 3200*256*4 = 3,276,800
    float* h1T   = (float*)(ws + 3276800);                           // 8192*256*4 = 8,388,608
    float* h2T   = (float*)(ws + 3276800 + 8388608);                 // 8,388,608
    float* stats = (float*)(ws + 3276800 + 2 * 8388608);             // 4 * 256 floats
    float* gs1 = stats;
    float* gq1 = stats + 256;
    float* gs2 = stats + 512;
    float* gq2 = stats + 768;

    init_kernel<<<256, 256, 0, stream>>>(out, stats);
    transpose_kernel<<<dim3(IN_DIM / 32, BATCH / 32), dim3(32, 8), 0, stream>>>(x, xT);

    // Layer 1: x -> h1 (no input norm)
    popcnt_kernel<false, false><<<O1_DIM, 256, 0, stream>>>(
        xT, sel1, w1, b1, nullptr, nullptr, nullptr, nullptr, 0.0f, h1T);

    // stats of h1 for layernorm 1
    stats_kernel<<<256, 256, 0, stream>>>(h1T, gs1, gq1, O1_DIM / 256);

    // Layer 2: layernorm(h1) folded in
    popcnt_kernel<true, false><<<O1_DIM, 256, 0, stream>>>(
        h1T, sel2, w2, b2, g1, be1, gs1, gq1, 1.0f / (float)O1_DIM, h2T);

    // stats of h2 for layernorm 2
    stats_kernel<<<256, 256, 0, stream>>>(h2T, gs2, gq2, O1_DIM / 256);

    // Layer 3: layernorm(h2) folded in, final group-sum via atomics into out
    popcnt_kernel<true, true><<<O3_DIM, 256, 0, stream>>>(
        h2T, sel3, w3, b3, g2, be2, gs2, gq2, 1.0f / (float)O1_DIM, out);
}

// Round 2
// 237.449 us; speedup vs baseline: 1.2817x; 1.2817x over previous
//
#include <hip/hip_runtime.h>
#include <hip/hip_fp16.h>
#include <hip/hip_bf16.h>
#include <stdint.h>

// Problem constants (from reference setup_inputs)
#define BATCH 256
#define PSEL  128
#define IN_DIM 3200
#define O1_DIM 8192
#define O3_DIM 4096

// ---------------------------------------------------------------------------
// init: out = -8.0 (final bias folded in, atomics accumulate on top),
//       stats accumulators (4 x 256 floats) = 0
// ---------------------------------------------------------------------------
__global__ __launch_bounds__(256) void init_kernel(float* __restrict__ out,
                                                   float* __restrict__ stats) {
    int i = blockIdx.x * 256 + threadIdx.x;   // grid = 256 blocks -> 65536 == out_size
    out[i] = -8.0f;
    if (i < 1024) stats[i] = 0.0f;
}

// ---------------------------------------------------------------------------
// transpose x [256, 3200] fp32 -> xT [3200, 256] fp16
// ---------------------------------------------------------------------------
__global__ __launch_bounds__(256) void transpose_kernel(const float* __restrict__ x,
                                                        __half* __restrict__ xT) {
    __shared__ float tile[32][33];
    int i0 = blockIdx.x * 32;   // input-dim tile (3200/32 = 100)
    int b0 = blockIdx.y * 32;   // batch tile    (256/32 = 8)
    int tx = threadIdx.x;       // 32
    int ty = threadIdx.y;       // 8
#pragma unroll
    for (int k = 0; k < 4; ++k)
        tile[ty + k * 8][tx] = x[(size_t)(b0 + ty + k * 8) * IN_DIM + i0 + tx];
    __syncthreads();
#pragma unroll
    for (int k = 0; k < 4; ++k)
        xT[(size_t)(i0 + ty + k * 8) * BATCH + b0 + tx] =
            __float2half(tile[tx][ty + k * 8]);
}

// ---------------------------------------------------------------------------
// stats: per-batch-column sum and sum-of-squares of hT [N, 256] (fp16 in, fp32 acc)
// grid = 256 blocks, each handles N/256 contiguous rows; coalesced reads.
// ---------------------------------------------------------------------------
__global__ __launch_bounds__(256) void stats_kernel(const __half* __restrict__ hT,
                                                    float* __restrict__ gsum,
                                                    float* __restrict__ gsq,
                                                    int rows_per_block) {
    int t = threadIdx.x;
    const __half* p = hT + (size_t)blockIdx.x * rows_per_block * BATCH + t;
    float s = 0.0f, q = 0.0f;
    for (int r = 0; r < rows_per_block; ++r) {
        float v = __half2float(p[(size_t)r * BATCH]);
        s += v;
        q = fmaf(v, v, q);
    }
    atomicAdd(&gsum[t], s);
    atomicAdd(&gsq[t], q);
}

// ---------------------------------------------------------------------------
// popcnt layer: one block (128 threads) per output o; thread t handles batch
// elements 2t and 2t+1 (one dword = 2 fp16 per gather row).
//   acc_b = sum_p A_p * actT[sel[o,p]*256 + b]
// With NORM, layernorm of the INPUT is folded algebraically:
//   sum_p w_p*((v-mu)*rs*g_p + be_p) = rs*acc + sumC - rs*mu*sumA
// where A_p = sigmoid(w_p)*g_p, C_p = sigmoid(w_p)*be_p.
// FINAL: atomicAdd sigmoid into out[b*256 + o/16] (pre-init'd to -8).
// ---------------------------------------------------------------------------
template <bool NORM, bool FINAL>
__global__ __launch_bounds__(128) void popcnt_kernel(
    const __half* __restrict__ actT,  // [Nin, 256] fp16
    const int* __restrict__ sel,      // [Nout, 128]
    const float* __restrict__ w,      // [Nout, 128]
    const float* __restrict__ bias,   // [Nout]
    const float* __restrict__ g,      // [Nin]  (NORM only)
    const float* __restrict__ be,     // [Nin]  (NORM only)
    const float* __restrict__ gsum,   // [256]  (NORM only)
    const float* __restrict__ gsq,    // [256]  (NORM only)
    float inv_n,                      // 1/Nin  (NORM only)
    void* __restrict__ outp)          // fp16 [Nout,256] or final fp32 [256,256]
{
    const int o = blockIdx.x;
    const int t = threadIdx.x;        // 0..127

    __shared__ alignas(16) uint32_t s_pair[2 * PSEL];  // {byte_offset, A_p} interleaved
    __shared__ float s_rA[PSEL], s_rC[PSEL];
    __shared__ float s_sums[2];

    {
        int idx = sel[o * PSEL + t];
        float ww = w[o * PSEL + t];
        float sw = 1.0f / (1.0f + __expf(-ww));   // resilu(w) == sigmoid(w)
        float a, c;
        if (NORM) {
            a = sw * g[idx];
            c = sw * be[idx];
        } else {
            a = sw;
            c = 0.0f;
        }
        s_pair[2 * t]     = (uint32_t)idx << 9;   // idx * 256 halves * 2 B
        s_pair[2 * t + 1] = __float_as_uint(a);
        if (NORM) { s_rA[t] = a; s_rC[t] = c; }
    }
    __syncthreads();

    if (NORM) {
        if (t < 64) {                 // wave 0 reduces sumA, sumC over 128 entries
            float va = s_rA[t] + s_rA[t + 64];
            float vc = s_rC[t] + s_rC[t + 64];
#pragma unroll
            for (int off = 32; off > 0; off >>= 1) {
                va += __shfl_down(va, off);
                vc += __shfl_down(vc, off);
            }
            if (t == 0) { s_sums[0] = va; s_sums[1] = vc; }
        }
    }

    // Main gather loop: 128 rows x 512B, each thread loads one dword (2 fp16).
    const char* base = (const char*)actT + (uint32_t)(t * 4);
    const uint4* pairs = (const uint4*)s_pair;
    float acc0 = 0.0f, acc1 = 0.0f;
#pragma unroll 8
    for (int p2 = 0; p2 < PSEL / 2; ++p2) {
        uint4 pr = pairs[p2];
        uint32_t d0 = *(const uint32_t*)(base + pr.x);
        uint32_t d1 = *(const uint32_t*)(base + pr.z);
        float a0 = __uint_as_float(pr.y);
        float a1 = __uint_as_float(pr.w);
        float2 f0 = __half22float2(*(const __half2*)&d0);
        float2 f1 = __half22float2(*(const __half2*)&d1);
        acc0 = fmaf(a0, f0.x, acc0);
        acc1 = fmaf(a0, f0.y, acc1);
        acc0 = fmaf(a1, f1.x, acc0);
        acc1 = fmaf(a1, f1.y, acc1);
    }
    __syncthreads();   // s_sums visible to all before epilogue

    float z0, z1;
    float bo = bias[o];
    if (NORM) {
        float2 ms = ((const float2*)gsum)[t];   // gsum[2t], gsum[2t+1]
        float2 qs = ((const float2*)gsq)[t];
        float m0 = ms.x * inv_n, m1 = ms.y * inv_n;
        float q0 = qs.x * inv_n, q1 = qs.y * inv_n;
        float rs0 = rsqrtf(q0 - m0 * m0 + 1e-12f);
        float rs1 = rsqrtf(q1 - m1 * m1 + 1e-12f);
        float sA = s_sums[0], sC = s_sums[1];
        z0 = rs0 * acc0 + sC - rs0 * m0 * sA - bo;
        z1 = rs1 * acc1 + sC - rs1 * m1 * sA - bo;
    } else {
        z0 = acc0 - bo;
        z1 = acc1 - bo;
    }
    float h0 = 1.0f / (1.0f + __expf(-z0));
    float h1 = 1.0f / (1.0f + __expf(-z1));

    if (FINAL) {
        float* out = (float*)outp;
        int grp = o >> 4;
        atomicAdd(&out[(2 * t) * 256 + grp], h0);      // out[b, o/16], init'd to -8
        atomicAdd(&out[(2 * t + 1) * 256 + grp], h1);
    } else {
        __half2 hv = __floats2half2_rn(h0, h1);
        *(__half2*)((__half*)outp + (size_t)o * BATCH + 2 * t) = hv;
    }
}

// ---------------------------------------------------------------------------
extern "C" void kernel_launch(void* const* d_in, const int* in_sizes, int n_in,
                              void* d_out, int out_size, void* d_ws, size_t ws_size,
                              hipStream_t stream) {
    const float* x    = (const float*)d_in[0];
    const int*   sel1 = (const int*)d_in[1];
    const float* w1   = (const float*)d_in[2];
    const float* b1   = (const float*)d_in[3];
    const float* g1   = (const float*)d_in[4];
    const float* be1  = (const float*)d_in[5];
    const int*   sel2 = (const int*)d_in[6];
    const float* w2   = (const float*)d_in[7];
    const float* b2   = (const float*)d_in[8];
    const float* g2   = (const float*)d_in[9];
    const float* be2  = (const float*)d_in[10];
    const int*   sel3 = (const int*)d_in[11];
    const float* w3   = (const float*)d_in[12];
    const float* b3   = (const float*)d_in[13];
    float* out = (float*)d_out;

    // workspace layout (fp16 activations)
    char* ws = (char*)d_ws;
    __half* xT  = (__half*)(ws);                          // 3200*256*2 = 1,638,400
    __half* h1T = (__half*)(ws + 1638400);                // 8192*256*2 = 4,194,304
    __half* h2T = (__half*)(ws + 1638400 + 4194304);      // 4,194,304
    float* stats = (float*)(ws + 1638400 + 2 * 4194304);  // 4 * 256 floats
    float* gs1 = stats;
    float* gq1 = stats + 256;
    float* gs2 = stats + 512;
    float* gq2 = stats + 768;

    init_kernel<<<256, 256, 0, stream>>>(out, stats);
    transpose_kernel<<<dim3(IN_DIM / 32, BATCH / 32), dim3(32, 8), 0, stream>>>(x, xT);

    // Layer 1: x -> h1 (no input norm)
    popcnt_kernel<false, false><<<O1_DIM, 128, 0, stream>>>(
        xT, sel1, w1, b1, nullptr, nullptr, nullptr, nullptr, 0.0f, h1T);

    // stats of h1 for layernorm 1
    stats_kernel<<<256, 256, 0, stream>>>(h1T, gs1, gq1, O1_DIM / 256);

    // Layer 2: layernorm(h1) folded in
    popcnt_kernel<true, false><<<O1_DIM, 128, 0, stream>>>(
        h1T, sel2, w2, b2, g1, be1, gs1, gq1, 1.0f / (float)O1_DIM, h2T);

    // stats of h2 for layernorm 2
    stats_kernel<<<256, 256, 0, stream>>>(h2T, gs2, gq2, O1_DIM / 256);

    // Layer 3: layernorm(h2) folded in, final group-sum via atomics into out
    popcnt_kernel<true, true><<<O3_DIM, 128, 0, stream>>>(
        h2T, sel3, w3, b3, g2, be2, gs2, gq2, 1.0f / (float)O1_DIM, out);
}